// Round 7
// baseline (199.343 us; speedup 1.0000x reference)
//
#include <hip/hip_runtime.h>
#include <math.h>

#define B_ 2
#define H_ 16
#define S_ 2048
#define D_ 72
#define LP 576
#define WEND 1088
#define DP 96        // padded D for qn/kn (3 chunks of 32)
#define DV 80        // padded dims for Vt (5 tiles of 16)
#define NQ (S_ - LP) // 1472 valid q rows

// attn LDS layout (32-bit words)
#define KS 50                    // K row stride (96 bf16 = 48 w + 2 pad)
#define VS 33                    // Vt row stride (64 bf16 = 32 w + 1 pad)
#define PW 33                    // P row stride (64 bf16 = 32 w + 1 pad)
#define VBASE (64 * KS)          // 3200
#define PBASE (VBASE + DV * VS)  // 5840
#define LDSW (PBASE + 4 * 16 * PW)  // 7952 words = 31808 B -> 5 blocks/CU

#define NPREP2 (B_ * H_ * S_ / 8)   // 8192 blocks, 8 rows each (2 rows/wave)
#define NVT    (32 * B_ * H_)       // 1024 blocks

typedef __bf16 bf16x8 __attribute__((ext_vector_type(8)));
typedef float f32x4 __attribute__((ext_vector_type(4)));

static __device__ __forceinline__ unsigned pack2bf(float a, float b) {
    __bf16 x = (__bf16)a, y = (__bf16)b;
    unsigned short ux = __builtin_bit_cast(unsigned short, x);
    unsigned short uy = __builtin_bit_cast(unsigned short, y);
    return (unsigned)ux | ((unsigned)uy << 16);
}

static __device__ __forceinline__ f32x4 mfma16(bf16x8 a, bf16x8 b, f32x4 c) {
    return __builtin_amdgcn_mfma_f32_16x16x32_bf16(a, b, c, 0, 0, 0);
}

// ---------- fused pre: prep (2 rows/wave, LDS-repacked uint4 stores) | vtrans (+zero) ----------
__global__ __launch_bounds__(256) void pre_kernel(
    const float* __restrict__ q, const float* __restrict__ k,
    const float* __restrict__ v,
    const float* __restrict__ pos, const float* __restrict__ pos_orig,
    const float* __restrict__ time_, const float* __restrict__ freqs,
    const float* __restrict__ t_freqs, const float* __restrict__ scale,
    unsigned* __restrict__ qn, unsigned* __restrict__ kn,
    unsigned short* __restrict__ vt, float* __restrict__ out)
{
    __shared__ __align__(16) float tile[64 * 77];  // vtrans; aliased by prep repack
    if (blockIdx.x < NPREP2) {
        unsigned short* shp = (unsigned short*)tile;  // [2][8][96] ushorts
        const int wave = threadIdx.x >> 6;
        const int lane = threadIdx.x & 63;
        const int j = lane & 31;               // lane within row
        const int rw = wave * 2 + (lane >> 5); // row within block (0..7)
        const int row = blockIdx.x * 8 + rw;
        const int s = row & (S_ - 1);
        const int h = (row >> 11) & (H_ - 1);
        const int b = row >> 15;
        const long base = (long)row * D_;
        const int p2 = (b * S_ + s) * 2;

        float oq1 = 0.f, oq2 = 0.f, ok1 = 0.f, ok2 = 0.f;
        float pq[6], pk[6];
        float ssq = 0.f, ssk = 0.f;
        if (j < 30) {
            const float x1q = q[base + j], x2q = q[base + j + 30];
            const float x1k = k[base + j], x2k = k[base + j + 30];
            const int g = j / 6, i = j - 6 * g;
            const float fh = freqs[96 + h * 6 + i];
            const float fw = freqs[h * 6 + i];
            const float ft = t_freqs[h * 6 + i];
            const float f  = (g < 2) ? fh : ((g < 4) ? fw : ft);
            const float by_o = pos_orig[p2 + 1] * 2.f - 1.f;
            const float by_p = pos[p2 + 1]      * 2.f - 1.f;
            const float bx_o = pos_orig[p2 + 0] * 2.f - 1.f;
            const float bx_p = pos[p2 + 0]      * 2.f - 1.f;
            const float bt   = time_[b * S_ + s];
            const float bv = (g == 0) ? by_o : (g == 1) ? by_p :
                             (g == 2) ? bx_o : (g == 3) ? bx_p : bt;
            float sn, cs;
            __sincosf(bv * f, &sn, &cs);
            oq1 = x1q * cs - x2q * sn;  oq2 = x2q * cs + x1q * sn;
            ok1 = x1k * cs - x2k * sn;  ok2 = x2k * cs + x1k * sn;
            ssq = oq1 * oq1 + oq2 * oq2;
            ssk = ok1 * ok1 + ok2 * ok2;
        } else {
            const int e0 = 60 + 6 * (j - 30);
            #pragma unroll
            for (int m = 0; m < 3; ++m) {
                const float2 a = *(const float2*)(q + base + e0 + 2 * m);
                const float2 c = *(const float2*)(k + base + e0 + 2 * m);
                pq[2 * m] = a.x; pq[2 * m + 1] = a.y;
                pk[2 * m] = c.x; pk[2 * m + 1] = c.y;
                ssq += a.x * a.x + a.y * a.y;
                ssk += c.x * c.x + c.y * c.y;
            }
        }
        #pragma unroll
        for (int m = 1; m < 32; m <<= 1) { ssq += __shfl_xor(ssq, m); ssk += __shfl_xor(ssk, m); }
        const float ss = sqrtf(scale[h]);
        const float fq = ss * rsqrtf(ssq + 1e-6f);
        const float fk = ss * rsqrtf(ssk + 1e-6f);

        unsigned short* sq_ = shp + rw * 96;          // [8][96] q
        unsigned short* sk_ = shp + 768 + rw * 96;    // k
        if (j < 30) {
            sq_[j]      = __builtin_bit_cast(unsigned short, (__bf16)(oq1 * fq));
            sq_[j + 30] = __builtin_bit_cast(unsigned short, (__bf16)(oq2 * fq));
            sk_[j]      = __builtin_bit_cast(unsigned short, (__bf16)(ok1 * fk));
            sk_[j + 30] = __builtin_bit_cast(unsigned short, (__bf16)(ok2 * fk));
        } else {
            const int e0 = 60 + 6 * (j - 30);
            #pragma unroll
            for (int m = 0; m < 6; ++m) {
                sq_[e0 + m] = __builtin_bit_cast(unsigned short, (__bf16)(pq[m] * fq));
                sk_[e0 + m] = __builtin_bit_cast(unsigned short, (__bf16)(pk[m] * fk));
            }
        }
        __syncthreads();
        // repack: 2 arrays x 8 rows x 12 uint4 = 192 coalesced stores
        const int t = threadIdx.x;
        if (t < 192) {
            const int arr = t / 96, rem = t - arr * 96;
            const int rr = rem / 12, seg = rem - rr * 12;
            uint4 val = make_uint4(0u, 0u, 0u, 0u);
            if (seg < 9) val = ((const uint4*)(shp + arr * 768 + rr * 96))[seg];
            unsigned* dst = (arr ? kn : qn) + ((long)(blockIdx.x * 8 + rr)) * 48;
            ((uint4*)dst)[seg] = val;
        }
    } else {
        // ---- vtrans (+ zero of out rows < LP) ----
        const int bx2 = blockIdx.x - NPREP2;
        const int st = bx2 & 31, bh = bx2 >> 5;
        const int s0 = st * 64;
        const int t = threadIdx.x;
        if (st < 9) {
            float4* o4 = (float4*)(out + (long)(bh * S_ + s0) * D_);
            for (int i = t; i < 1152; i += 256) o4[i] = make_float4(0.f, 0.f, 0.f, 0.f);
        }
        for (int i = t; i < 1152; i += 256) {
            const int r = i / 18, c = i - r * 18;
            const float4 g = ((const float4*)v)[((long)(bh * S_ + s0 + r) * 18) + c];
            float* d = &tile[r * 77 + c * 4];
            d[0] = g.x; d[1] = g.y; d[2] = g.z; d[3] = g.w;
        }
        __syncthreads();
        for (int i = t; i < 1280; i += 256) {
            const int dd = i >> 4, s4 = i & 15;
            float f0 = 0.f, f1 = 0.f, f2 = 0.f, f3 = 0.f;
            if (dd < D_) {
                f0 = tile[(s4 * 4 + 0) * 77 + dd];
                f1 = tile[(s4 * 4 + 1) * 77 + dd];
                f2 = tile[(s4 * 4 + 2) * 77 + dd];
                f3 = tile[(s4 * 4 + 3) * 77 + dd];
            }
            uint2 o; o.x = pack2bf(f0, f1); o.y = pack2bf(f2, f3);
            ((uint2*)vt)[((((long)bh * DV + dd) << 11) + s0 + s4 * 4) >> 2] = o;
        }
    }
}

// ---------- attention: 4 waves x 16 q-rows, 64-key LDS tiles, split-K over blockIdx.z ----------
__global__ __launch_bounds__(256) void attn_kernel(
    const unsigned short* __restrict__ qn, const unsigned short* __restrict__ kn,
    const unsigned short* __restrict__ vt,
    float* __restrict__ po, float* __restrict__ pden)
{
    __shared__ __align__(16) unsigned lds[LDSW];
    const int bh = blockIdx.y;
    const int kz = blockIdx.z;
    const int q0 = LP + blockIdx.x * 64;
    const int tid = threadIdx.x;
    const int w = tid >> 6, lane = tid & 63;
    const int quad = lane >> 4, l16 = lane & 15;
    const int q0w = q0 + 16 * w;
    const bool causal = (q0 < WEND);
    const int ntiles = causal ? (q0 >> 6) + 1 : (WEND >> 6);

    const unsigned short* qn_b = qn + (((long)bh) << 11) * DP;
    const unsigned short* kn_b = kn + (((long)bh) << 11) * DP;
    const unsigned short* vt_b = vt + (long)bh * DV * S_;

    bf16x8 qf[3];
    #pragma unroll
    for (int c = 0; c < 3; ++c)
        qf[c] = *(const bf16x8*)(qn_b + (long)(q0w + l16) * DP + c * 32 + quad * 8);

    f32x4 o[5];
    float den[4];
    #pragma unroll
    for (int dt = 0; dt < 5; ++dt) { o[dt][0]=0.f; o[dt][1]=0.f; o[dt][2]=0.f; o[dt][3]=0.f; }
    #pragma unroll
    for (int r = 0; r < 4; ++r) den[r] = 0.f;

    unsigned* Ps = lds + PBASE + w * (16 * PW);

    for (int kt = kz; kt < ntiles; kt += 2) {
        const int k0 = kt * 64;
        __syncthreads();
        #pragma unroll
        for (int ii = 0; ii < 3; ++ii) {
            const int i = tid + ii * 256;
            const int r = i / 12, seg = i - r * 12;
            const int key = k0 + 32 * (r >> 5) + 2 * (r & 15) + ((r >> 4) & 1);
            *(uint4*)(lds + r * KS + seg * 4) = *(const uint4*)(kn_b + (long)key * DP + seg * 8);
        }
        for (int i = tid; i < 640; i += 256) {
            const int rr = i >> 3, seg = i & 7;
            *(uint4*)(lds + VBASE + rr * VS + seg * 4) =
                *(const uint4*)(vt_b + (((long)rr) << 11) + k0 + seg * 8);
        }
        __syncthreads();

        f32x4 acc[4];
        #pragma unroll
        for (int G = 0; G < 4; ++G) { acc[G][0]=0.f; acc[G][1]=0.f; acc[G][2]=0.f; acc[G][3]=0.f; }
        #pragma unroll
        for (int c = 0; c < 3; ++c)
            #pragma unroll
            for (int G = 0; G < 4; ++G) {
                const bf16x8 kf = *(const bf16x8*)(lds + (16 * G + l16) * KS + c * 16 + quad * 4);
                acc[G] = mfma16(qf[c], kf, acc[G]);
            }
        #pragma unroll
        for (int g2 = 0; g2 < 2; ++g2) {
            const int kb = k0 + 32 * g2 + 2 * l16;
            #pragma unroll
            for (int r = 0; r < 4; ++r) {
                const int qa = q0w + quad * 4 + r;
                float p0 = acc[2 * g2][r], p1 = acc[2 * g2 + 1][r];
                p0 = (!causal || kb     <= qa) ? __expf(p0) : 0.f;
                p1 = (!causal || kb + 1 <= qa) ? __expf(p1) : 0.f;
                const __bf16 pb0 = (__bf16)p0, pb1 = (__bf16)p1;
                den[r] += (float)pb0 + (float)pb1;
                Ps[(quad * 4 + r) * PW + g2 * 16 + l16] =
                    (unsigned)__builtin_bit_cast(unsigned short, pb0) |
                    ((unsigned)__builtin_bit_cast(unsigned short, pb1) << 16);
            }
        }
        const bf16x8 pa0 = *(const bf16x8*)(Ps + l16 * PW + quad * 4);
        const bf16x8 pa1 = *(const bf16x8*)(Ps + l16 * PW + 16 + quad * 4);
        #pragma unroll
        for (int dt = 0; dt < 5; ++dt) {
            const bf16x8 vf0 = *(const bf16x8*)(lds + VBASE + (dt * 16 + l16) * VS + quad * 4);
            const bf16x8 vf1 = *(const bf16x8*)(lds + VBASE + (dt * 16 + l16) * VS + 16 + quad * 4);
            o[dt] = mfma16(pa0, vf0, o[dt]);
            o[dt] = mfma16(pa1, vf1, o[dt]);
        }
    }

    #pragma unroll
    for (int r = 0; r < 4; ++r)
        #pragma unroll
        for (int x = 1; x < 16; x <<= 1) den[r] += __shfl_xor(den[r], x);

    if (kz == 1 && !causal) {  // diagonal self-key k == q (window rows), once
        float* PsD = (float*)Ps;
        float sp = 0.f;
        #pragma unroll
        for (int c = 0; c < 3; ++c) {
            const bf16x8 kd = *(const bf16x8*)(kn_b + (long)(q0w + l16) * DP + c * 32 + quad * 8);
            #pragma unroll
            for (int j = 0; j < 8; ++j) sp += (float)qf[c][j] * (float)kd[j];
        }
        sp += __shfl_xor(sp, 16);
        sp += __shfl_xor(sp, 32);
        if (quad == 0) PsD[l16] = __expf(sp);
        #pragma unroll
        for (int r = 0; r < 4; ++r) {
            const float pd = PsD[quad * 4 + r];
            den[r] += pd;
            const int qa = q0w + quad * 4 + r;
            #pragma unroll
            for (int dt = 0; dt < 5; ++dt) {
                const unsigned short uv = vt_b[(((long)(dt * 16 + l16)) << 11) + qa];
                o[dt][r] += pd * (float)__builtin_bit_cast(__bf16, uv);
            }
        }
    }

    // store partials: po[(kz*32+bh)][rq][80], pden[(kz*32+bh)][rq]
    const long pobase = ((long)(kz * 32 + bh)) * NQ * DV;
    const long pdbase = ((long)(kz * 32 + bh)) * NQ;
    #pragma unroll
    for (int r = 0; r < 4; ++r) {
        const int rq = blockIdx.x * 64 + 16 * w + quad * 4 + r;
        #pragma unroll
        for (int dt = 0; dt < 5; ++dt)
            po[pobase + (long)rq * DV + dt * 16 + l16] = o[dt][r];
        if (l16 == 0) pden[pdbase + rq] = den[r];
    }
}

// ---------- combine: out = (po0+po1)/(den0+den1) ----------
__global__ __launch_bounds__(256) void combine_kernel(
    const float* __restrict__ po, const float* __restrict__ pden,
    float* __restrict__ out)
{
    const int t = threadIdx.x;
    const int rowid = blockIdx.x * 16 + (t >> 4);   // 0..47103 (bh*NQ + rq)
    const int d0 = t & 15;
    const int bh = rowid / NQ;
    const int rq = rowid - bh * NQ;
    const long p0 = ((long)bh) * NQ * DV + (long)rq * DV;
    const long p1 = ((long)(32 + bh)) * NQ * DV + (long)rq * DV;
    const float den = pden[(long)bh * NQ + rq] + pden[(long)(32 + bh) * NQ + rq];
    const float inv = 1.f / den;
    float* orow = out + ((long)bh * S_ + LP + rq) * D_;
    #pragma unroll
    for (int j = 0; j < 5; ++j) {
        const int d = d0 + 16 * j;
        if (d < D_) orow[d] = (po[p0 + d] + po[p1 + d]) * inv;
    }
}

extern "C" void kernel_launch(void* const* d_in, const int* in_sizes, int n_in,
                              void* d_out, int out_size, void* d_ws, size_t ws_size,
                              hipStream_t stream) {
    const float* q        = (const float*)d_in[0];
    const float* k        = (const float*)d_in[1];
    const float* v        = (const float*)d_in[2];
    const float* pos      = (const float*)d_in[3];
    const float* pos_orig = (const float*)d_in[4];
    const float* time_    = (const float*)d_in[5];
    const float* freqs    = (const float*)d_in[6];
    const float* t_freqs  = (const float*)d_in[7];
    const float* scale    = (const float*)d_in[8];
    float* out = (float*)d_out;

    unsigned* qn = (unsigned*)d_ws;                                   // 12.6 MB
    unsigned* kn = qn + (size_t)B_ * H_ * S_ * 48;                    // 12.6 MB
    unsigned short* vt = (unsigned short*)(kn + (size_t)B_ * H_ * S_ * 48);  // 10.5 MB
    float* po = (float*)(vt + (size_t)B_ * H_ * DV * S_);             // 30.2 MB
    float* pden = po + (size_t)2 * B_ * H_ * NQ * DV;                 // 0.38 MB

    pre_kernel<<<dim3(NPREP2 + NVT), dim3(256), 0, stream>>>(
        q, k, v, pos, pos_orig, time_, freqs, t_freqs, scale, qn, kn, vt, out);
    attn_kernel<<<dim3(NQ / 64, B_ * H_, 2), dim3(256), 0, stream>>>(
        (const unsigned short*)qn, (const unsigned short*)kn, vt, po, pden);
    combine_kernel<<<dim3(B_ * H_ * NQ / 16), dim3(256), 0, stream>>>(po, pden, out);
}